// Round 1
// baseline (1998.265 us; speedup 1.0000x reference)
//
#include <hip/hip_runtime.h>

// Sizes
#define T 70
#define B 64
#define E 512
#define H 512
#define V 10000
#define TB (T*B)            // 4480
#define SLOT (H*B)          // 32768 floats per (t) state slot
#define LOGITS_N (T*B*V)    // 44800000

__device__ __forceinline__ float ftanh(float x) {
    // tanh(x) = 1 - 2/(exp(2x)+1); saturates correctly at +/-inf
    float e = __expf(2.0f * x);
    return 1.0f - 2.0f / (e + 1.0f);
}

// ---------------------------------------------------------------------------
// 1) Embedding gather: X[t][b][e] (row-major) = emb_table[ids[t][b]][e]
// ---------------------------------------------------------------------------
__global__ __launch_bounds__(256) void gather_emb(const int* __restrict__ ids,
                                                  const float* __restrict__ emb,
                                                  float* __restrict__ X) {
    int i = blockIdx.x * 256 + threadIdx.x;       // float4 index
    if (i >= TB * (E / 4)) return;
    int tok = i >> 7;                             // E/4 = 128 float4 per token
    int e4 = i & 127;
    int id = ids[tok];
    ((float4*)X)[i] = ((const float4*)emb)[id * 128 + e4];
}

// ---------------------------------------------------------------------------
// 2) Transpose initial hidden (L,B,H) row-major -> k4-packed (H/4, B, 4) slots
// ---------------------------------------------------------------------------
__global__ __launch_bounds__(256) void hinit_k(const float* __restrict__ hidden,
                                               float* __restrict__ H0,
                                               float* __restrict__ H1) {
    int i = blockIdx.x * 256 + threadIdx.x;       // [0, 2*SLOT)
    if (i >= 2 * SLOT) return;
    int l = i >> 15, r = i & (SLOT - 1);
    int k4 = r >> 8, q = r & 255, b = q >> 2, kk = q & 3;
    int h = k4 * 4 + kk;
    float v = hidden[l * SLOT + b * H + h];
    (l ? H1 : H0)[r] = v;
}

// ---------------------------------------------------------------------------
// 3) P0 = X @ W0x.T + b0   -> layout (T, N=512, B=64)
//    M=4480 (t,b), N=512, K=512.  A = X row-major (TB, E)
// ---------------------------------------------------------------------------
__global__ __launch_bounds__(256) void gemm_p0(const float* __restrict__ X,
                                               const float* __restrict__ W0,
                                               const float* __restrict__ b0v,
                                               float* __restrict__ P0) {
    __shared__ float As[32][68];   // [k][b]
    __shared__ float Ws[32][68];   // [k][n]
    int t = blockIdx.y;
    int n0 = blockIdx.x * 64;
    int tid = threadIdx.x;
    int bq = tid & 15;    // b0 = bq*4
    int nq = tid >> 4;    // n local = nq*4
    const float* A = X + t * 64 * E;
    float acc[4][4] = {{0.f}};

    for (int kc = 0; kc < 512; kc += 32) {
        for (int i = tid; i < 512; i += 256) {
            int bb = i >> 3, kq = i & 7;
            float4 a = *(const float4*)(A + bb * E + kc + kq * 4);
            As[kq*4+0][bb] = a.x; As[kq*4+1][bb] = a.y;
            As[kq*4+2][bb] = a.z; As[kq*4+3][bb] = a.w;
        }
        for (int i = tid; i < 512; i += 256) {
            int nn = i >> 3, kq = i & 7;
            float4 w = *(const float4*)(W0 + (size_t)(n0 + nn) * 1024 + kc + kq * 4);
            Ws[kq*4+0][nn] = w.x; Ws[kq*4+1][nn] = w.y;
            Ws[kq*4+2][nn] = w.z; Ws[kq*4+3][nn] = w.w;
        }
        __syncthreads();
#pragma unroll
        for (int kk = 0; kk < 32; kk++) {
            float4 a = *(const float4*)&As[kk][bq * 4];
            float4 w = *(const float4*)&Ws[kk][nq * 4];
            acc[0][0] += a.x*w.x; acc[0][1] += a.x*w.y; acc[0][2] += a.x*w.z; acc[0][3] += a.x*w.w;
            acc[1][0] += a.y*w.x; acc[1][1] += a.y*w.y; acc[1][2] += a.y*w.z; acc[1][3] += a.y*w.w;
            acc[2][0] += a.z*w.x; acc[2][1] += a.z*w.y; acc[2][2] += a.z*w.z; acc[2][3] += a.z*w.w;
            acc[3][0] += a.w*w.x; acc[3][1] += a.w*w.y; acc[3][2] += a.w*w.z; acc[3][3] += a.w*w.w;
        }
        __syncthreads();
    }
#pragma unroll
    for (int j = 0; j < 4; j++) {
        int n = n0 + nq * 4 + j;
        float bias = b0v[n];
        float4 r = make_float4(acc[0][j] + bias, acc[1][j] + bias,
                               acc[2][j] + bias, acc[3][j] + bias);
        *(float4*)(P0 + (size_t)t * SLOT + n * 64 + bq * 4) = r;
    }
}

// ---------------------------------------------------------------------------
// 4) Pipelined recurrence step.  Launch s = 0..70:
//    blocks 0..63  : layer0 step s   (if s < 70):
//        h0[s] = tanh(P0[s] + W0h @ h0[s-1])            [K=512]
//    blocks 64..127: layer1 step s-1 (if s >= 1):
//        h1[s-1] = tanh(b1 + W1x @ h0[s-1] + W1h @ h1[s-2])   [K=1024]
//    State slots: Hl[slot] holds h_l at t = slot-1; slot 0 = initial hidden.
//    Slots are k4-packed: addr = k4*256 + b*4 + (k&3).
// ---------------------------------------------------------------------------
__global__ __launch_bounds__(256) void chain_step_k(const float* __restrict__ P0,
                                                    float* __restrict__ H0,
                                                    float* __restrict__ H1,
                                                    const float* __restrict__ W0,
                                                    const float* __restrict__ W1,
                                                    const float* __restrict__ b1v,
                                                    int step) {
    int tid = threadIdx.x;
    int b = tid & 63;
    int wv = __builtin_amdgcn_readfirstlane(tid >> 6);
    int bid = blockIdx.x;

    if (bid < 64) {
        if (step >= T) return;
        int n0 = bid * 8 + wv * 2;
        const float4* A = (const float4*)(H0 + (size_t)step * SLOT);  // h0[step-1]
        const float* w0 = W0 + (size_t)n0 * 1024 + 512;
        const float* w1 = W0 + (size_t)(n0 + 1) * 1024 + 512;
        float acc0 = P0[(size_t)step * SLOT + n0 * 64 + b];
        float acc1 = P0[(size_t)step * SLOT + (n0 + 1) * 64 + b];
#pragma unroll 4
        for (int k4 = 0; k4 < 128; k4++) {
            float4 a = A[k4 * 64 + b];
            int k = k4 * 4;
            acc0 += a.x * w0[k] + a.y * w0[k+1] + a.z * w0[k+2] + a.w * w0[k+3];
            acc1 += a.x * w1[k] + a.y * w1[k+1] + a.z * w1[k+2] + a.w * w1[k+3];
        }
        float o0 = ftanh(acc0), o1 = ftanh(acc1);
        float* dst = H0 + (size_t)(step + 1) * SLOT + (n0 >> 2) * 256 + b * 4 + (n0 & 3);
        dst[0] = o0; dst[1] = o1;
    } else {
        if (step < 1) return;
        int t1 = step - 1;
        int n0 = (bid - 64) * 8 + wv * 2;
        const float4* Aa = (const float4*)(H0 + (size_t)(t1 + 1) * SLOT); // h0[t1]
        const float4* Ab = (const float4*)(H1 + (size_t)t1 * SLOT);       // h1[t1-1]
        const float* wa0 = W1 + (size_t)n0 * 1024;
        const float* wa1 = W1 + (size_t)(n0 + 1) * 1024;
        const float* wb0 = wa0 + 512;
        const float* wb1 = wa1 + 512;
        float acc0 = b1v[n0], acc1 = b1v[n0 + 1];
#pragma unroll 4
        for (int k4 = 0; k4 < 128; k4++) {
            float4 a = Aa[k4 * 64 + b];
            float4 c = Ab[k4 * 64 + b];
            int k = k4 * 4;
            acc0 += a.x * wa0[k] + a.y * wa0[k+1] + a.z * wa0[k+2] + a.w * wa0[k+3];
            acc1 += a.x * wa1[k] + a.y * wa1[k+1] + a.z * wa1[k+2] + a.w * wa1[k+3];
            acc0 += c.x * wb0[k] + c.y * wb0[k+1] + c.z * wb0[k+2] + c.w * wb0[k+3];
            acc1 += c.x * wb1[k] + c.y * wb1[k+1] + c.z * wb1[k+2] + c.w * wb1[k+3];
        }
        float o0 = ftanh(acc0), o1 = ftanh(acc1);
        float* dst = H1 + (size_t)(t1 + 1) * SLOT + (n0 >> 2) * 256 + b * 4 + (n0 & 3);
        dst[0] = o0; dst[1] = o1;
    }
}

// ---------------------------------------------------------------------------
// 5) logits[t][b][v] = tanh(H1[t] @ Wout.T + bout)
//    M=4480, N=10000, K=512.  A = H1 slots (k4-packed), out row-major (T,B,V)
// ---------------------------------------------------------------------------
__global__ __launch_bounds__(256) void gemm_logits(const float* __restrict__ H1,
                                                   const float* __restrict__ Wout,
                                                   const float* __restrict__ boutv,
                                                   float* __restrict__ out) {
    __shared__ float As[32][68];   // [k][b]
    __shared__ float Ws[32][68];   // [k][v]
    int t = blockIdx.y;
    int v0 = blockIdx.x * 64;
    int tid = threadIdx.x;
    int bq = tid & 15;
    int vq = tid >> 4;
    const float* A = H1 + (size_t)(t + 1) * SLOT;
    float acc[4][4] = {{0.f}};

    for (int kc = 0; kc < 512; kc += 32) {
        for (int i = tid; i < 512; i += 256) {
            float4 a = ((const float4*)A)[kc * 16 + i];    // contiguous k4-packed
            int k4 = i >> 6, bb = i & 63;
            As[k4*4+0][bb] = a.x; As[k4*4+1][bb] = a.y;
            As[k4*4+2][bb] = a.z; As[k4*4+3][bb] = a.w;
        }
        for (int i = tid; i < 512; i += 256) {
            int vv = i >> 3, kq = i & 7;
            int v = v0 + vv;
            float4 w = (v < V) ? *(const float4*)(Wout + (size_t)v * 512 + kc + kq * 4)
                               : make_float4(0.f, 0.f, 0.f, 0.f);
            Ws[kq*4+0][vv] = w.x; Ws[kq*4+1][vv] = w.y;
            Ws[kq*4+2][vv] = w.z; Ws[kq*4+3][vv] = w.w;
        }
        __syncthreads();
#pragma unroll
        for (int kk = 0; kk < 32; kk++) {
            float4 a = *(const float4*)&As[kk][bq * 4];
            float4 w = *(const float4*)&Ws[kk][vq * 4];
            acc[0][0] += a.x*w.x; acc[0][1] += a.x*w.y; acc[0][2] += a.x*w.z; acc[0][3] += a.x*w.w;
            acc[1][0] += a.y*w.x; acc[1][1] += a.y*w.y; acc[1][2] += a.y*w.z; acc[1][3] += a.y*w.w;
            acc[2][0] += a.z*w.x; acc[2][1] += a.z*w.y; acc[2][2] += a.z*w.z; acc[2][3] += a.z*w.w;
            acc[3][0] += a.w*w.x; acc[3][1] += a.w*w.y; acc[3][2] += a.w*w.z; acc[3][3] += a.w*w.w;
        }
        __syncthreads();
    }
    int vb = v0 + vq * 4;
    if (vb < V) {
        float4 bo = *(const float4*)(boutv + vb);
#pragma unroll
        for (int i = 0; i < 4; i++) {
            int b = bq * 4 + i;
            float4 r = make_float4(ftanh(acc[i][0] + bo.x),
                                   ftanh(acc[i][1] + bo.y),
                                   ftanh(acc[i][2] + bo.z),
                                   ftanh(acc[i][3] + bo.w));
            *(float4*)(out + ((size_t)t * 64 + b) * V + vb) = r;
        }
    }
}

// ---------------------------------------------------------------------------
// 6) Final hidden -> d_out tail, (L,B,H) row-major
// ---------------------------------------------------------------------------
__global__ __launch_bounds__(256) void hfinal_k(const float* __restrict__ H0,
                                                const float* __restrict__ H1,
                                                float* __restrict__ out) {
    int i = blockIdx.x * 256 + threadIdx.x;       // [0, 2*SLOT)
    if (i >= 2 * SLOT) return;
    int l = i >> 15, r = i & (SLOT - 1);
    int b = r >> 9, h = r & 511;
    const float* Hp = l ? H1 : H0;
    out[LOGITS_N + i] = Hp[(size_t)T * SLOT + (h >> 2) * 256 + b * 4 + (h & 3)];
}

// ---------------------------------------------------------------------------
extern "C" void kernel_launch(void* const* d_in, const int* in_sizes, int n_in,
                              void* d_out, int out_size, void* d_ws, size_t ws_size,
                              hipStream_t stream) {
    const int*   ids    = (const int*)d_in[0];
    const float* hidden = (const float*)d_in[1];
    const float* emb    = (const float*)d_in[2];
    const float* W0     = (const float*)d_in[3];
    const float* b0v    = (const float*)d_in[4];
    const float* W1     = (const float*)d_in[5];
    const float* b1v    = (const float*)d_in[6];
    const float* Wout   = (const float*)d_in[7];
    const float* boutv  = (const float*)d_in[8];
    float* out = (float*)d_out;
    float* ws  = (float*)d_ws;

    float* X  = ws;                                   // TB*E      = 2,293,760
    float* P0 = ws + 2293760;                         // T*SLOT    = 2,293,760
    float* H0 = ws + 4587520;                         // 71*SLOT   = 2,326,528
    float* H1 = ws + 6914048;                         // 71*SLOT   = 2,326,528

    gather_emb<<<2240, 256, 0, stream>>>(ids, emb, X);
    hinit_k<<<256, 256, 0, stream>>>(hidden, H0, H1);
    gemm_p0<<<dim3(8, T), 256, 0, stream>>>(X, W0, b0v, P0);
    for (int s = 0; s <= T; s++) {
        chain_step_k<<<128, 256, 0, stream>>>(P0, H0, H1, W0, W1, b1v, s);
    }
    gemm_logits<<<dim3(157, T), 256, 0, stream>>>(H1, Wout, boutv, out);
    hfinal_k<<<256, 256, 0, stream>>>(H0, H1, out);
}